// Round 1
// baseline (310.475 us; speedup 1.0000x reference)
//
#include <hip/hip_runtime.h>

// NeRF volume render: B rays x S=64 samples.
// Layout v2: 16 lanes per ray, 4 consecutive samples per lane (4 rays/wave).
//   - float4 loads (64 B/lane, fully coalesced)
//   - local cumprod over 4 samples in registers (3 mults)
//   - 4-level width-16 multiplicative scan (5 shuffles/wave, amortized 1.25/ray)
//   - 4-level butterfly reduce over 4 accumulators (4 shuffles/ray)
// vs v1 (wave-per-ray): 31 shuffles/ray, 16 B/lane scalar loads, 4x the waves.
//
// alpha_i = 1 - exp(-sigma_i)
// T_i = prod_{j<i} (1 - alpha_j + 1e-10)   (exclusive cumprod)
// w_i = alpha_i * T_i
// rgb_map = sum_i w_i * rgb_i ; depth_map = sum_i w_i * t_i, t = linspace(2,6,64)

#define NSAMP 64
#define RAYS_PER_WAVE 4
#define WAVES_PER_BLOCK 4
#define RAYS_PER_BLOCK (RAYS_PER_WAVE * WAVES_PER_BLOCK)

__global__ __launch_bounds__(256) void nerf_render_kernel(
    const float* __restrict__ rgb,     // [B, 64, 3]
    const float* __restrict__ sigma,   // [B, 64]
    float* __restrict__ rgb_map,       // [B, 3]
    float* __restrict__ depth_map,     // [B]
    int n_rays)
{
    const int lane = threadIdx.x & 63;
    const int wave = threadIdx.x >> 6;
    const int g    = lane >> 4;        // ray within wave (0..3)
    const int q    = lane & 15;        // position within ray group; samples 4q..4q+3
    const int ray  = blockIdx.x * RAYS_PER_BLOCK + wave * RAYS_PER_WAVE + g;
    if (ray >= n_rays) return;

    // ---- Loads: fully coalesced float4 (16 B x 64 lanes = 1 KiB/instr) ----
    const float4 sg = *(const float4*)(sigma + (size_t)ray * NSAMP + q * 4);
    const float* rp = rgb + ((size_t)ray * NSAMP + q * 4) * 3;
    const float4 c0 = *(const float4*)(rp + 0);   // r0 g0 b0 r1
    const float4 c1 = *(const float4*)(rp + 4);   // g1 b1 r2 g2
    const float4 c2 = *(const float4*)(rp + 8);   // b2 r3 g3 b3

    // ---- Per-sample alpha / transmittance factor ----
    // v_k = 1 - alpha_k + 1e-10 = exp(-sigma_k) + 1e-10
    const float e0 = expf(-sg.x);
    const float e1 = expf(-sg.y);
    const float e2 = expf(-sg.z);
    const float e3 = expf(-sg.w);
    const float v0 = e0 + 1e-10f;
    const float v1 = e1 + 1e-10f;
    const float v2 = e2 + 1e-10f;
    const float v3 = e3 + 1e-10f;
    const float a0 = 1.0f - e0;
    const float a1 = 1.0f - e1;
    const float a2 = 1.0f - e2;
    const float a3 = 1.0f - e3;

    // ---- Local inclusive prefix products over this lane's 4 samples ----
    const float p1 = v0;
    const float p2 = p1 * v1;
    const float p3 = p2 * v2;
    const float p4 = p3 * v3;          // product of all 4

    // ---- Width-16 inclusive multiplicative scan of p4 across the ray group ----
    float P = p4;
    #pragma unroll
    for (int d = 1; d < 16; d <<= 1) {
        const float o = __shfl_up(P, d, 16);
        if (q >= d) P *= o;
    }
    // Exclusive base transmittance for this lane's first sample.
    float Tb = __shfl_up(P, 1, 16);
    if (q == 0) Tb = 1.0f;

    // ---- Weights ----
    const float w0 = a0 * Tb;
    const float w1 = a1 * (Tb * p1);
    const float w2 = a2 * (Tb * p2);
    const float w3 = a3 * (Tb * p3);

    // t = linspace(2, 6, 64): t_i = 2 + i * (4/63)
    const float h  = 4.0f / 63.0f;
    const float t0 = 2.0f + (float)(4 * q) * h;
    const float t1 = t0 + h;
    const float t2 = t1 + h;
    const float t3 = t2 + h;

    // ---- Per-lane partial sums ----
    float cr = w0 * c0.x + w1 * c0.w + w2 * c1.z + w3 * c2.y;
    float cg = w0 * c0.y + w1 * c1.x + w2 * c1.w + w3 * c2.z;
    float cb = w0 * c0.z + w1 * c1.y + w2 * c2.x + w3 * c2.w;
    float cd = w0 * t0   + w1 * t1   + w2 * t2   + w3 * t3;

    // ---- Butterfly reduce across the 16-lane ray group ----
    #pragma unroll
    for (int d = 8; d >= 1; d >>= 1) {
        cr += __shfl_xor(cr, d, 16);
        cg += __shfl_xor(cg, d, 16);
        cb += __shfl_xor(cb, d, 16);
        cd += __shfl_xor(cd, d, 16);
    }

    if (q == 0) {
        float* o = rgb_map + (size_t)ray * 3;
        o[0] = cr;
        o[1] = cg;
        o[2] = cb;
        depth_map[ray] = cd;
    }
}

extern "C" void kernel_launch(void* const* d_in, const int* in_sizes, int n_in,
                              void* d_out, int out_size, void* d_ws, size_t ws_size,
                              hipStream_t stream) {
    const float* rgb   = (const float*)d_in[0];   // [B, 64, 3]
    const float* sigma = (const float*)d_in[1];   // [B, 64]
    const int n_rays = in_sizes[1] / NSAMP;

    float* rgb_map   = (float*)d_out;                        // first B*3 floats
    float* depth_map = (float*)d_out + (size_t)n_rays * 3;   // next B floats

    const int blocks = (n_rays + RAYS_PER_BLOCK - 1) / RAYS_PER_BLOCK;
    nerf_render_kernel<<<blocks, WAVES_PER_BLOCK * 64, 0, stream>>>(
        rgb, sigma, rgb_map, depth_map, n_rays);
}

// Round 3
// 309.828 us; speedup vs baseline: 1.0021x; 1.0021x over previous
//
#include <hip/hip_runtime.h>

// NeRF volume render: B rays x S=64 samples.
// Layout v3: 16 lanes per ray, 4 samples per lane (4 rays/wave), with rgb
// staged through LDS so ALL global loads are fully contiguous:
//   - sigma: 1 float4/lane, 1 KiB/wave contiguous (as in v2)
//   - rgb:   3x float4/lane at lane-stride 16 B (1 KiB/wave/instr, zero gaps)
//            -> LDS (linear, 12 KB/block) -> 3x ds_read_b128 per-ray chunk.
// v2's direct rgb loads were 48-B-strided across lanes (3x cache-line touches
// per instr); that coalescer overhead is the theorized ~3.8 vs 6.3 TB/s gap.
// Each wave stages and reads ONLY its own 3 KB region -> no __syncthreads.
//
// alpha_i = 1 - exp(-sigma_i)
// T_i = prod_{j<i} (1 - alpha_j + 1e-10)   (exclusive cumprod)
// w_i = alpha_i * T_i
// rgb_map = sum_i w_i * rgb_i ; depth_map = sum_i w_i * t_i, t = linspace(2,6,64)

#define NSAMP 64
#define RAYS_PER_WAVE 4
#define WAVES_PER_BLOCK 4
#define RAYS_PER_BLOCK (RAYS_PER_WAVE * WAVES_PER_BLOCK)   // 16

__global__ __launch_bounds__(256) void nerf_render_kernel(
    const float* __restrict__ rgb,     // [B, 64, 3]
    const float* __restrict__ sigma,   // [B, 64]
    float* __restrict__ rgb_map,       // [B, 3]
    float* __restrict__ depth_map,     // [B]
    int n_rays)
{
    // 16 rays x 192 floats, linear (mirrors global layout of this block's rgb)
    __shared__ float srgb[RAYS_PER_BLOCK * NSAMP * 3];     // 12 KB

    const int lane = threadIdx.x & 63;
    const int wave = threadIdx.x >> 6;
    const int g    = lane >> 4;        // ray within wave (0..3)
    const int q    = lane & 15;        // position within ray; samples 4q..4q+3
    const int block_ray0 = blockIdx.x * RAYS_PER_BLOCK;
    const int ray  = block_ray0 + wave * RAYS_PER_WAVE + g;

    float4 c0, c1, c2;   // 12 rgb floats for samples 4q..4q+3 of this ray

    // Fast path: this wave's 4 rays are all in range -> coalesced LDS staging.
    if (block_ray0 + wave * RAYS_PER_WAVE + RAYS_PER_WAVE <= n_rays) {
        // Wave w owns floats [w*768, w*768+768) of the block's 12288-float
        // rgb chunk. Three contiguous 1-KiB loads (lane-stride 16 B).
        const float* gbase = rgb + (size_t)block_ray0 * (NSAMP * 3)
                                 + wave * 768 + lane * 4;
        const float4 s0 = *(const float4*)(gbase + 0);
        const float4 s1 = *(const float4*)(gbase + 256);
        const float4 s2 = *(const float4*)(gbase + 512);

        float* lbase = srgb + wave * 768 + lane * 4;
        *(float4*)(lbase + 0)   = s0;
        *(float4*)(lbase + 256) = s1;
        *(float4*)(lbase + 512) = s2;

        // Read back this lane's per-ray 48-B chunk (same-wave dep: compiler
        // inserts lgkmcnt wait; no barrier needed — wave reads its own region).
        // Bank view (dwords): 12q + {0,4,8} mod 32 -> only (q, q+8) alias = 2-way.
        const float* rb = srgb + (wave * RAYS_PER_WAVE + g) * (NSAMP * 3) + q * 12;
        c0 = *(const float4*)(rb + 0);
        c1 = *(const float4*)(rb + 4);
        c2 = *(const float4*)(rb + 8);
    } else {
        // Tail path (never taken for B=262144): v2-style direct strided loads.
        if (ray >= n_rays) return;
        const float* rp = rgb + ((size_t)ray * NSAMP + q * 4) * 3;
        c0 = *(const float4*)(rp + 0);
        c1 = *(const float4*)(rp + 4);
        c2 = *(const float4*)(rp + 8);
    }

    if (ray >= n_rays) return;

    // Sigma: fully contiguous 1 KiB/wave float4 load.
    const float4 sg = *(const float4*)(sigma + (size_t)ray * NSAMP + q * 4);

    // ---- Per-sample alpha / transmittance factor ----
    // v_k = 1 - alpha_k + 1e-10 = exp(-sigma_k) + 1e-10
    const float e0 = expf(-sg.x);
    const float e1 = expf(-sg.y);
    const float e2 = expf(-sg.z);
    const float e3 = expf(-sg.w);
    const float v0 = e0 + 1e-10f;
    const float v1 = e1 + 1e-10f;
    const float v2 = e2 + 1e-10f;
    const float v3 = e3 + 1e-10f;
    const float a0 = 1.0f - e0;
    const float a1 = 1.0f - e1;
    const float a2 = 1.0f - e2;
    const float a3 = 1.0f - e3;

    // ---- Local inclusive prefix products over this lane's 4 samples ----
    const float p1 = v0;
    const float p2 = p1 * v1;
    const float p3 = p2 * v2;
    const float p4 = p3 * v3;          // product of all 4

    // ---- Width-16 inclusive multiplicative scan of p4 across the ray group ----
    float P = p4;
    #pragma unroll
    for (int d = 1; d < 16; d <<= 1) {
        const float o = __shfl_up(P, d, 16);
        if (q >= d) P *= o;
    }
    // Exclusive base transmittance for this lane's first sample.
    float Tb = __shfl_up(P, 1, 16);
    if (q == 0) Tb = 1.0f;

    // ---- Weights ----
    const float w0 = a0 * Tb;
    const float w1 = a1 * (Tb * p1);
    const float w2 = a2 * (Tb * p2);
    const float w3 = a3 * (Tb * p3);

    // t = linspace(2, 6, 64): t_i = 2 + i * (4/63)
    const float h  = 4.0f / 63.0f;
    const float t0 = 2.0f + (float)(4 * q) * h;
    const float t1 = t0 + h;
    const float t2 = t1 + h;
    const float t3 = t2 + h;

    // ---- Per-lane partial sums ----
    float cr = w0 * c0.x + w1 * c0.w + w2 * c1.z + w3 * c2.y;
    float cg = w0 * c0.y + w1 * c1.x + w2 * c1.w + w3 * c2.z;
    float cb = w0 * c0.z + w1 * c1.y + w2 * c2.x + w3 * c2.w;
    float cd = w0 * t0   + w1 * t1   + w2 * t2   + w3 * t3;

    // ---- Butterfly reduce across the 16-lane ray group ----
    #pragma unroll
    for (int d = 8; d >= 1; d >>= 1) {
        cr += __shfl_xor(cr, d, 16);
        cg += __shfl_xor(cg, d, 16);
        cb += __shfl_xor(cb, d, 16);
        cd += __shfl_xor(cd, d, 16);
    }

    if (q == 0) {
        float* o = rgb_map + (size_t)ray * 3;
        o[0] = cr;
        o[1] = cg;
        o[2] = cb;
        depth_map[ray] = cd;
    }
}

extern "C" void kernel_launch(void* const* d_in, const int* in_sizes, int n_in,
                              void* d_out, int out_size, void* d_ws, size_t ws_size,
                              hipStream_t stream) {
    const float* rgb   = (const float*)d_in[0];   // [B, 64, 3]
    const float* sigma = (const float*)d_in[1];   // [B, 64]
    const int n_rays = in_sizes[1] / NSAMP;

    float* rgb_map   = (float*)d_out;                        // first B*3 floats
    float* depth_map = (float*)d_out + (size_t)n_rays * 3;   // next B floats

    const int blocks = (n_rays + RAYS_PER_BLOCK - 1) / RAYS_PER_BLOCK;
    nerf_render_kernel<<<blocks, WAVES_PER_BLOCK * 64, 0, stream>>>(
        rgb, sigma, rgb_map, depth_map, n_rays);
}